// Round 15
// baseline (93.294 us; speedup 1.0000x reference)
//
#include <hip/hip_runtime.h>
#include <hip/hip_bf16.h>
#include <math.h>

// Fused net, round 15: cut phase-2 LDS bytes via the zero-K structure.
// conv1 K-window: only kx<=4 real; B rows k>=20 are prepacked ZEROS. The A-frag's
// second 8B chunk (k = 16+4*grp..) is real only for grp==0 (kx4); for grp 1-3 it
// multiplies zero B rows. Predicate that read on grp==0 (exec-masked, 16/64 lanes)
// and feed register zeros otherwise: phase-2 A LDS traffic -37.5%, exact result.
// Everything else identical to round 14 (RS1=160, 2 img/block, fc1-MFMA).

typedef __attribute__((ext_vector_type(8))) short bf16x8;
typedef __attribute__((ext_vector_type(4))) float f32x4;

union Frag { short4 h[2]; bf16x8 v; };

// prepack-side conversion (off critical path): integer RNE, known-good
static __device__ __forceinline__ unsigned short f2bf(float f) {
    union { float f; unsigned u; } v; v.f = f;
    unsigned r = v.u + 0x7FFFu + ((v.u >> 16) & 1u);
    return (unsigned short)(r >> 16);
}
// kernel-side: native cast
static __device__ __forceinline__ unsigned short nbf(float f) {
    union { __hip_bfloat16 h; unsigned short u; } c;
    c.h = __float2bfloat16(f);
    return c.u;
}

#define MFMA(a, b, c) __builtin_amdgcn_mfma_f32_16x16x32_bf16((a), (b), (c), 0, 0, 0)

// ---------------- B-fragment prepack: 31 frags x 64 lanes x 8 bf16 ----------------
__global__ __launch_bounds__(64)
void prepack(const float* __restrict__ W, const float* __restrict__ w1,
             const float* __restrict__ w2, unsigned short* __restrict__ ws) {
    const int fid = blockIdx.x;
    const int lane = threadIdx.x;
    const int col = lane & 15, grp = lane >> 4;
    unsigned short tmp[8];
    #pragma unroll
    for (int e = 0; e < 8; ++e) {
        const int kap = 16 * (e >> 2) + 4 * grp + (e & 3);   // 0..31
        float v = 0.f;
        if (fid < 6) {
            const int ks = fid / 3, nt = fid % 3;
            const int k = 32 * ks + kap, j = 16 * nt + col;
            if (k < 48) v = W[j * 48 + k];
        } else if (fid < 11) {
            const int ky = fid - 6;
            const int kx = kap >> 2, icp = kap & 3;
            if (kx < 5 && icp < 3 && col < 10)
                v = w1[col * 75 + icp * 25 + ky * 5 + kx];
        } else {
            const int r = fid - 11, nt = r / 10, ky = (r % 10) >> 1, s = r & 1;
            const int idx = 32 * s + kap;
            const int kx = idx / 12, icp = idx % 12, oc = 16 * nt + col;
            if (kx < 5 && icp < 10 && oc < 20)
                v = w2[oc * 250 + icp * 25 + ky * 5 + kx];
        }
        tmp[e] = f2bf(v);
    }
    Frag f;
    f.h[0] = make_short4((short)tmp[0], (short)tmp[1], (short)tmp[2], (short)tmp[3]);
    f.h[1] = make_short4((short)tmp[4], (short)tmp[5], (short)tmp[6], (short)tmp[7]);
    *(bf16x8*)(ws + fid * 512 + lane * 8) = f.v;
}

// ---------------- fc1 A-frag prepack: 64 frags (kstep*4+mt) at ws+16384 ----------------
__global__ __launch_bounds__(64)
void pack_fc1(const float* __restrict__ fw1, unsigned short* __restrict__ ws) {
    const int fid = blockIdx.x;                 // 0..63 = kstep*4 + mt
    const int kstep = fid >> 2, mt = fid & 3;
    const int lane = threadIdx.x;
    const int col = lane & 15, grp = lane >> 4;
    const int outr = 16 * mt + col;
    unsigned short tmp[8];
    #pragma unroll
    for (int e = 0; e < 8; ++e) {
        const int kap = 16 * (e >> 2) + 4 * grp + (e & 3);
        const int kk = 32 * kstep + kap;
        float v = (outr < 50 && kk < 500) ? fw1[outr * 500 + kk] : 0.f;
        tmp[e] = f2bf(v);
    }
    Frag f;
    f.h[0] = make_short4((short)tmp[0], (short)tmp[1], (short)tmp[2], (short)tmp[3]);
    f.h[1] = make_short4((short)tmp[4], (short)tmp[5], (short)tmp[6], (short)tmp[7]);
    *(bf16x8*)(ws + 16384 + fid * 512 + lane * 8) = f.v;
}

// ---------------- main fused kernel: one block (512 thr) per TWO images ----------------
#define RS1 160              // s_img row stride: RS1/4==8 mod 16 -> conflict-free phase-2 reads
#define IMG_SZ 5184          // 32*RS1 + 64 tail (ushorts)
#define RS2 168              // s_h1 row stride (elems): 14 cols * 12ch
#define H1_SZ 2416           // 14*RS2 + 64 tail

__global__ __launch_bounds__(512)
void fused_net(const float* __restrict__ x,    // [B,32,32,3] NHWC f32
               const unsigned short* __restrict__ ws, // prepacked frags
               const float* __restrict__ b1,   // [10]
               const float* __restrict__ b2,   // [20]
               const float* __restrict__ fb1,  // [50]
               const float* __restrict__ fw2,  // [10,50]
               const float* __restrict__ fb2,  // [10]
               float* __restrict__ out)        // [B,10]
{
    const int tid  = threadIdx.x;
    const int wave = __builtin_amdgcn_readfirstlane(tid >> 6);   // 0..7
    const int img  = wave >> 2;                                  // 0..1
    const int wv   = wave & 3;                                   // old 4-wave id
    const int lane = tid & 63;
    const int col16 = lane & 15, grp = lane >> 4;

    __shared__ __align__(16) unsigned short s_pool[2 * IMG_SZ];
    __shared__ __align__(16) unsigned short s_h1[2 * H1_SZ];
    __shared__ __align__(16) unsigned short s_h2b[2 * 512];   // h2 bf16, zero-padded 500..511
    __shared__ __align__(16) float s_aux[416];   // part 256 | f1 2x64 | lg 2x16

    unsigned short* s_img = s_pool + img * IMG_SZ;
    unsigned short* s_h1i = s_h1 + img * H1_SZ;
    unsigned short* s_b2  = s_pool;
    float* s_part = s_aux;          // [khalf*2+im][64]
    float* s_f1   = s_aux + 256;    // [im][64]
    float* s_lg   = s_aux + 384;    // [im][16]

    const size_t bb = (size_t)(2 * blockIdx.x + img);   // batch index of this wave's image

    // ---------------- Phase 1: linear via MFMA -> s_img (HWC4 bf16) ----------------
    {
        const int blkA = 16 * wv + col16;
        const float* xb = x + bb * 3072 + (blkA >> 3) * 384 + (blkA & 7) * 12;
        const int k0 = 4 * grp,      o0 = (k0 / 12) * 96 + (k0 % 12);
        const int k1 = 16 + 4 * grp, o1 = (k1 / 12) * 96 + (k1 % 12);
        const int k2 = 32 + 4 * grp, o2 = (k2 / 12) * 96 + (k2 % 12);
        const float4 fa = *(const float4*)(xb + o0);
        const float4 fb = *(const float4*)(xb + o1);
        const float4 fc = *(const float4*)(xb + o2);
        Frag a0, a1;
        a0.h[0] = make_short4((short)nbf(fa.x), (short)nbf(fa.y), (short)nbf(fa.z), (short)nbf(fa.w));
        a0.h[1] = make_short4((short)nbf(fb.x), (short)nbf(fb.y), (short)nbf(fb.z), (short)nbf(fb.w));
        a1.h[0] = make_short4((short)nbf(fc.x), (short)nbf(fc.y), (short)nbf(fc.z), (short)nbf(fc.w));
        a1.h[1] = make_short4(0, 0, 0, 0);        // k>=48 pad: zero (also avoids OOB x reads)

        #pragma unroll
        for (int nt = 0; nt < 3; ++nt) {
            Frag bl0, bl1;                        // streamed from L2 (shared by both images)
            bl0.v = *(const bf16x8*)(ws + nt * 512 + lane * 8);
            bl1.v = *(const bf16x8*)(ws + (3 + nt) * 512 + lane * 8);
            f32x4 acc = {0.f, 0.f, 0.f, 0.f};
            acc = MFMA(a0.v, bl0.v, acc);
            acc = MFMA(a1.v, bl1.v, acc);
            const int j = 16 * nt + col16;                 // output k' index
            const int di = j / 12, dj = (j % 12) / 3, cch = j % 3;
            #pragma unroll
            for (int r = 0; r < 4; ++r) {
                const int blk = 16 * wv + 4 * grp + r;     // C row = block id
                const int row = (blk >> 3) * 4 + di, cp = (blk & 7) * 4 + dj;
                s_img[row * RS1 + cp * 4 + cch] = nbf(acc[r]);
            }
        }
    }
    // zero pad-channel 3, row pads (cols 128..159), LDS tails, h2b pads
    for (int p = tid; p < 2048; p += 512) {                 // ch-3 of 1024 px per image
        unsigned short* si = s_pool + (p >> 10) * IMG_SZ;
        const int q = p & 1023;
        si[(q >> 5) * RS1 + (q & 31) * 4 + 3] = 0;
    }
    for (int p = tid; p < 2048; p += 512) {                 // 32 pad cols x 32 rows per image
        unsigned short* si = s_pool + (p >> 10) * IMG_SZ;
        const int q = p & 1023;
        si[(q >> 5) * RS1 + 128 + (q & 31)] = 0;
    }
    if (tid < 128) s_pool[(tid >> 6) * IMG_SZ + 32 * RS1 + (tid & 63)] = 0;
    if (tid < 128) s_h1[(tid >> 6) * H1_SZ + 14 * RS2 + (tid & 63)] = 0;
    if (tid < 24) s_h2b[(tid / 12) * 512 + 500 + (tid % 12)] = 0;
    __syncthreads();

    // ---------------- Phase 2: conv1+pool+relu via MFMA -> s_h1 (HWC12 bf16) ----------------
    // Two M-tiles per iteration; A h[1] read only for grp==0 (k 16..19 = kx4);
    // grp 1-3's h[1] hits only zero B rows -> register zeros, no LDS read.
    {
        Frag bc1[5];
        #pragma unroll
        for (int f = 0; f < 5; ++f)
            bc1[f].v = *(const bf16x8*)(ws + (6 + f) * 512 + lane * 8);
        const float bias1 = b1[col16 < 10 ? col16 : 0];
        const int sub = col16 & 3, qc = col16 >> 2;
        const short4 z4 = make_short4(0, 0, 0, 0);

        for (int u = 0; u < 6; ++u) {
            const int t0 = wv + 8 * u, t1 = t0 + 4;        // both <= 47
            const int q0 = 4 * t0 + qc, q1 = 4 * t1 + qc;
            const int base0 = (2 * (q0 / 14) + (sub >> 1)) * RS1 + (2 * (q0 % 14) + (sub & 1)) * 4 + 4 * grp;
            const int base1 = (2 * (q1 / 14) + (sub >> 1)) * RS1 + (2 * (q1 % 14) + (sub & 1)) * 4 + 4 * grp;
            f32x4 acc0 = {0.f, 0.f, 0.f, 0.f}, acc1 = {0.f, 0.f, 0.f, 0.f};
            #pragma unroll
            for (int ky = 0; ky < 5; ++ky) {
                Frag a0, a1;
                a0.h[0] = *(const short4*)&s_img[base0 + ky * RS1];
                a1.h[0] = *(const short4*)&s_img[base1 + ky * RS1];
                a0.h[1] = z4;
                a1.h[1] = z4;
                if (grp == 0) {                            // exec-masked: 16/64 lanes
                    a0.h[1] = *(const short4*)&s_img[base0 + ky * RS1 + 16];
                    a1.h[1] = *(const short4*)&s_img[base1 + ky * RS1 + 16];
                }
                acc0 = MFMA(a0.v, bc1[ky].v, acc0);
                acc1 = MFMA(a1.v, bc1[ky].v, acc1);
            }
            if (col16 < 12) {
                const int qo0 = 4 * t0 + grp, qo1 = 4 * t1 + grp;
                const float pm0 = fmaxf(fmaxf(acc0[0], acc0[1]), fmaxf(acc0[2], acc0[3]));
                const float pm1 = fmaxf(fmaxf(acc1[0], acc1[1]), fmaxf(acc1[2], acc1[3]));
                s_h1i[(qo0 / 14) * RS2 + (qo0 % 14) * 12 + col16] =
                    (col16 < 10) ? nbf(fmaxf(pm0 + bias1, 0.f)) : (unsigned short)0;
                s_h1i[(qo1 / 14) * RS2 + (qo1 % 14) * 12 + col16] =
                    (col16 < 10) ? nbf(fmaxf(pm1 + bias1, 0.f)) : (unsigned short)0;
            }
        }
        if (wv == 0) {                                     // tail tile t = 48
            const int q = 192 + qc;
            const int base = (2 * (q / 14) + (sub >> 1)) * RS1 + (2 * (q % 14) + (sub & 1)) * 4 + 4 * grp;
            f32x4 acc = {0.f, 0.f, 0.f, 0.f};
            #pragma unroll
            for (int ky = 0; ky < 5; ++ky) {
                Frag a;
                a.h[0] = *(const short4*)&s_img[base + ky * RS1];
                a.h[1] = z4;
                if (grp == 0)
                    a.h[1] = *(const short4*)&s_img[base + ky * RS1 + 16];
                acc = MFMA(a.v, bc1[ky].v, acc);
            }
            if (col16 < 12) {
                const int qo = 192 + grp;
                const float pm = fmaxf(fmaxf(acc[0], acc[1]), fmaxf(acc[2], acc[3]));
                s_h1i[(qo / 14) * RS2 + (qo % 14) * 12 + col16] =
                    (col16 < 10) ? nbf(fmaxf(pm + bias1, 0.f)) : (unsigned short)0;
            }
        }
    }
    __syncthreads();

    // ---- re-stage conv2 B-frags (20KB) into s_pool (both s_img now dead) ----
    {
        const uint4* src = (const uint4*)(ws + 11 * 512);   // frags 11..30, 1280 uint4
        uint4* dst = (uint4*)s_pool;
        dst[tid]       = src[tid];
        dst[tid + 512] = src[tid + 512];
        if (tid < 256) dst[tid + 1024] = src[tid + 1024];
    }
    __syncthreads();

    // ---------------- Phase 3: conv2+pool+relu via MFMA -> s_h2b (bf16, flatten order) ----------------
    {
        const int oc1 = 16 + col16;
        const float bias20 = b2[col16];                    // col16 <= 15 < 20
        const float bias21 = b2[oc1 < 20 ? oc1 : 0];

        int baseA[2];
        #pragma unroll
        for (int tt = 0; tt < 2; ++tt) {
            const int t = wv + 4 * tt;                     // t in {wv, wv+4}
            int q = 4 * t + (col16 >> 2); if (q > 24) q = 24;   // clamp keeps reads in-bounds
            const int sub = col16 & 3;
            const int oi = q / 5, oj = q % 5;
            const int ci = 2 * oi + (sub >> 1), cj = 2 * oj + (sub & 1);
            baseA[tt] = ci * RS2 + cj * 12 + 4 * grp;
        }

        f32x4 accA0 = {0.f,0.f,0.f,0.f}, accA1 = {0.f,0.f,0.f,0.f};   // tile tt=0: N-tile 0/1
        f32x4 accB0 = {0.f,0.f,0.f,0.f}, accB1 = {0.f,0.f,0.f,0.f};   // tile tt=1
        #pragma unroll
        for (int ky = 0; ky < 5; ++ky) {
            #pragma unroll
            for (int s = 0; s < 2; ++s) {
                Frag bb0, bb1;
                bb0.v = *(const bf16x8*)(s_b2 + (ky * 2 + s) * 512 + lane * 8);
                bb1.v = *(const bf16x8*)(s_b2 + (10 + ky * 2 + s) * 512 + lane * 8);
                Frag a0, a1;
                a0.h[0] = *(const short4*)&s_h1i[baseA[0] + ky * RS2 + 32 * s];
                a0.h[1] = *(const short4*)&s_h1i[baseA[0] + ky * RS2 + 32 * s + 16];
                a1.h[0] = *(const short4*)&s_h1i[baseA[1] + ky * RS2 + 32 * s];
                a1.h[1] = *(const short4*)&s_h1i[baseA[1] + ky * RS2 + 32 * s + 16];
                accA0 = MFMA(a0.v, bb0.v, accA0);
                accA1 = MFMA(a0.v, bb1.v, accA1);
                accB0 = MFMA(a1.v, bb0.v, accB0);
                accB1 = MFMA(a1.v, bb1.v, accB1);
            }
        }
        unsigned short* h2 = s_h2b + img * 512;
        #pragma unroll
        for (int tt = 0; tt < 2; ++tt) {
            const int t = wv + 4 * tt;
            if (t < 7) {
                const f32x4 c0 = tt ? accB0 : accA0;
                const f32x4 c1 = tt ? accB1 : accA1;
                const int qo = 4 * t + grp;
                if (qo < 25) {
                    const float p0 = fmaxf(fmaxf(c0[0], c0[1]), fmaxf(c0[2], c0[3]));
                    h2[col16 * 25 + qo] = nbf(fmaxf(p0 + bias20, 0.f));
                    if (oc1 < 20) {
                        const float p1 = fmaxf(fmaxf(c1[0], c1[1]), fmaxf(c1[2], c1[3]));
                        h2[oc1 * 25 + qo] = nbf(fmaxf(p1 + bias21, 0.f));
                    }
                }
            }
        }
    }
    __syncthreads();

    // ---------------- Phase 4: fc1 via MFMA: C[out][img], wave = (khalf=img, mt=wv) ----------------
    {
        const int mt = wv, khalf = img;
        const int imc = col16 < 2 ? col16 : 0;     // B col = image; cols 2..15 unused
        f32x4 acc = {0.f, 0.f, 0.f, 0.f};
        #pragma unroll
        for (int j = 0; j < 8; ++j) {
            const int kstep = 8 * khalf + j;
            Frag af, bfv;
            af.v = *(const bf16x8*)(ws + 16384 + (kstep * 4 + mt) * 512 + lane * 8);
            bfv.h[0] = *(const short4*)&s_h2b[imc * 512 + 32 * kstep + 4 * grp];
            bfv.h[1] = *(const short4*)&s_h2b[imc * 512 + 32 * kstep + 16 + 4 * grp];
            acc = MFMA(af.v, bfv.v, acc);
        }
        if (col16 < 2) {
            #pragma unroll
            for (int r = 0; r < 4; ++r)
                s_part[(khalf * 2 + col16) * 64 + 16 * mt + 4 * grp + r] = acc[r];
        }
    }
    __syncthreads();
    if (tid < 128) {                                // combine k-halves, +bias, relu
        const int im = tid >> 6, o = tid & 63;
        const float a = s_part[im * 64 + o] + s_part[(2 + im) * 64 + o];
        if (o < 50) s_f1[im * 64 + o] = fmaxf(a + fb1[o], 0.f);
    }
    __syncthreads();

    // ---------------- Phase 5: fc2 (50->10), both images ----------------
    if (tid < 20) {
        const int im = (tid >= 10) ? 1 : 0;
        const int r = tid - 10 * im;
        const float* wr = fw2 + r * 50;
        const float* f1 = s_f1 + im * 64;
        float a = fb2[r];
        for (int k = 0; k < 50; ++k) a += f1[k] * wr[k];
        s_lg[im * 16 + r] = a;
    }
    __syncthreads();

    // ---------------- Phase 6: log_softmax, both images ----------------
    if (tid < 20) {
        const int im = (tid >= 10) ? 1 : 0;
        const int r = tid - 10 * im;
        const float* lg = s_lg + im * 16;
        float m = lg[0];
        for (int k = 1; k < 10; ++k) m = fmaxf(m, lg[k]);
        float s = 0.f;
        for (int k = 0; k < 10; ++k) s += expf(lg[k] - m);
        out[(2 * (size_t)blockIdx.x + im) * 10 + r] = lg[r] - m - logf(s);
    }
}

extern "C" void kernel_launch(void* const* d_in, const int* in_sizes, int n_in,
                              void* d_out, int out_size, void* d_ws, size_t ws_size,
                              hipStream_t stream) {
    const float* x   = (const float*)d_in[0];
    const float* W   = (const float*)d_in[1];
    const float* w1  = (const float*)d_in[2];
    const float* b1  = (const float*)d_in[3];
    const float* w2  = (const float*)d_in[4];
    const float* b2  = (const float*)d_in[5];
    const float* fw1 = (const float*)d_in[6];
    const float* fb1 = (const float*)d_in[7];
    const float* fw2 = (const float*)d_in[8];
    const float* fb2 = (const float*)d_in[9];
    float* o = (float*)d_out;
    unsigned short* wsp = (unsigned short*)d_ws;

    const int B = in_sizes[0] / 3072;
    prepack<<<dim3(31), dim3(64), 0, stream>>>(W, w1, w2, wsp);
    pack_fc1<<<dim3(64), dim3(64), 0, stream>>>(fw1, wsp);
    fused_net<<<dim3(B / 2), dim3(512), 0, stream>>>(x, wsp, b1, b2, fb1, fw2, fb2, o);
}

// Round 16
// 89.575 us; speedup vs baseline: 1.0415x; 1.0415x over previous
//
#include <hip/hip_runtime.h>
#include <hip/hip_bf16.h>
#include <math.h>

// Fused net, round 16: kill phase-2's division-heavy addressing (the ~38% VALU chunk).
// q -> (row,col) maps are pure functions of q in [0,196): precompute two 196-entry
// int LDS tables once per block (tA = A-read base, tW = h1-write base); per u-iter
// 4 broadcast ds_read_b32 + adds replace ~40 magic-div VALU ops. Round-15's
// exec-masked A-read REVERTED (regression: +5% VALU, -16 occupancy).
// Everything else = round 14 (RS1=160, 2 img/block, fc1-MFMA, staged conv2 B).

typedef __attribute__((ext_vector_type(8))) short bf16x8;
typedef __attribute__((ext_vector_type(4))) float f32x4;

union Frag { short4 h[2]; bf16x8 v; };

// prepack-side conversion (off critical path): integer RNE, known-good
static __device__ __forceinline__ unsigned short f2bf(float f) {
    union { float f; unsigned u; } v; v.f = f;
    unsigned r = v.u + 0x7FFFu + ((v.u >> 16) & 1u);
    return (unsigned short)(r >> 16);
}
// kernel-side: native cast
static __device__ __forceinline__ unsigned short nbf(float f) {
    union { __hip_bfloat16 h; unsigned short u; } c;
    c.h = __float2bfloat16(f);
    return c.u;
}

#define MFMA(a, b, c) __builtin_amdgcn_mfma_f32_16x16x32_bf16((a), (b), (c), 0, 0, 0)

// ---------------- B-fragment prepack: 31 frags x 64 lanes x 8 bf16 ----------------
__global__ __launch_bounds__(64)
void prepack(const float* __restrict__ W, const float* __restrict__ w1,
             const float* __restrict__ w2, unsigned short* __restrict__ ws) {
    const int fid = blockIdx.x;
    const int lane = threadIdx.x;
    const int col = lane & 15, grp = lane >> 4;
    unsigned short tmp[8];
    #pragma unroll
    for (int e = 0; e < 8; ++e) {
        const int kap = 16 * (e >> 2) + 4 * grp + (e & 3);   // 0..31
        float v = 0.f;
        if (fid < 6) {
            const int ks = fid / 3, nt = fid % 3;
            const int k = 32 * ks + kap, j = 16 * nt + col;
            if (k < 48) v = W[j * 48 + k];
        } else if (fid < 11) {
            const int ky = fid - 6;
            const int kx = kap >> 2, icp = kap & 3;
            if (kx < 5 && icp < 3 && col < 10)
                v = w1[col * 75 + icp * 25 + ky * 5 + kx];
        } else {
            const int r = fid - 11, nt = r / 10, ky = (r % 10) >> 1, s = r & 1;
            const int idx = 32 * s + kap;
            const int kx = idx / 12, icp = idx % 12, oc = 16 * nt + col;
            if (kx < 5 && icp < 10 && oc < 20)
                v = w2[oc * 250 + icp * 25 + ky * 5 + kx];
        }
        tmp[e] = f2bf(v);
    }
    Frag f;
    f.h[0] = make_short4((short)tmp[0], (short)tmp[1], (short)tmp[2], (short)tmp[3]);
    f.h[1] = make_short4((short)tmp[4], (short)tmp[5], (short)tmp[6], (short)tmp[7]);
    *(bf16x8*)(ws + fid * 512 + lane * 8) = f.v;
}

// ---------------- fc1 A-frag prepack: 64 frags (kstep*4+mt) at ws+16384 ----------------
__global__ __launch_bounds__(64)
void pack_fc1(const float* __restrict__ fw1, unsigned short* __restrict__ ws) {
    const int fid = blockIdx.x;                 // 0..63 = kstep*4 + mt
    const int kstep = fid >> 2, mt = fid & 3;
    const int lane = threadIdx.x;
    const int col = lane & 15, grp = lane >> 4;
    const int outr = 16 * mt + col;
    unsigned short tmp[8];
    #pragma unroll
    for (int e = 0; e < 8; ++e) {
        const int kap = 16 * (e >> 2) + 4 * grp + (e & 3);
        const int kk = 32 * kstep + kap;
        float v = (outr < 50 && kk < 500) ? fw1[outr * 500 + kk] : 0.f;
        tmp[e] = f2bf(v);
    }
    Frag f;
    f.h[0] = make_short4((short)tmp[0], (short)tmp[1], (short)tmp[2], (short)tmp[3]);
    f.h[1] = make_short4((short)tmp[4], (short)tmp[5], (short)tmp[6], (short)tmp[7]);
    *(bf16x8*)(ws + 16384 + fid * 512 + lane * 8) = f.v;
}

// ---------------- main fused kernel: one block (512 thr) per TWO images ----------------
#define RS1 160              // s_img row stride: RS1/4==8 mod 16 -> conflict-free phase-2 reads
#define IMG_SZ 5184          // 32*RS1 + 64 tail (ushorts)
#define RS2 168              // s_h1 row stride (elems): 14 cols * 12ch
#define H1_SZ 2416           // 14*RS2 + 64 tail

__global__ __launch_bounds__(512)
void fused_net(const float* __restrict__ x,    // [B,32,32,3] NHWC f32
               const unsigned short* __restrict__ ws, // prepacked frags
               const float* __restrict__ b1,   // [10]
               const float* __restrict__ b2,   // [20]
               const float* __restrict__ fb1,  // [50]
               const float* __restrict__ fw2,  // [10,50]
               const float* __restrict__ fb2,  // [10]
               float* __restrict__ out)        // [B,10]
{
    const int tid  = threadIdx.x;
    const int wave = __builtin_amdgcn_readfirstlane(tid >> 6);   // 0..7
    const int img  = wave >> 2;                                  // 0..1
    const int wv   = wave & 3;                                   // old 4-wave id
    const int lane = tid & 63;
    const int col16 = lane & 15, grp = lane >> 4;

    __shared__ __align__(16) unsigned short s_pool[2 * IMG_SZ];
    __shared__ __align__(16) unsigned short s_h1[2 * H1_SZ];
    __shared__ __align__(16) unsigned short s_h2b[2 * 512];   // h2 bf16, zero-padded 500..511
    __shared__ __align__(16) float s_aux[416];   // part 256 | f1 2x64 | lg 2x16
    __shared__ int s_tA[196];                    // q -> A-read base (2*(q/14)*RS1 + 8*(q%14))
    __shared__ int s_tW[196];                    // q -> h1-write base ((q/14)*RS2 + 12*(q%14))

    unsigned short* s_img = s_pool + img * IMG_SZ;
    unsigned short* s_h1i = s_h1 + img * H1_SZ;
    unsigned short* s_b2  = s_pool;
    float* s_part = s_aux;          // [khalf*2+im][64]
    float* s_f1   = s_aux + 256;    // [im][64]
    float* s_lg   = s_aux + 384;    // [im][16]

    const size_t bb = (size_t)(2 * blockIdx.x + img);   // batch index of this wave's image

    // ---------------- Phase 1: linear via MFMA -> s_img (HWC4 bf16) ----------------
    {
        const int blkA = 16 * wv + col16;
        const float* xb = x + bb * 3072 + (blkA >> 3) * 384 + (blkA & 7) * 12;
        const int k0 = 4 * grp,      o0 = (k0 / 12) * 96 + (k0 % 12);
        const int k1 = 16 + 4 * grp, o1 = (k1 / 12) * 96 + (k1 % 12);
        const int k2 = 32 + 4 * grp, o2 = (k2 / 12) * 96 + (k2 % 12);
        const float4 fa = *(const float4*)(xb + o0);
        const float4 fb = *(const float4*)(xb + o1);
        const float4 fc = *(const float4*)(xb + o2);
        Frag a0, a1;
        a0.h[0] = make_short4((short)nbf(fa.x), (short)nbf(fa.y), (short)nbf(fa.z), (short)nbf(fa.w));
        a0.h[1] = make_short4((short)nbf(fb.x), (short)nbf(fb.y), (short)nbf(fb.z), (short)nbf(fb.w));
        a1.h[0] = make_short4((short)nbf(fc.x), (short)nbf(fc.y), (short)nbf(fc.z), (short)nbf(fc.w));
        a1.h[1] = make_short4(0, 0, 0, 0);        // k>=48 pad: zero (also avoids OOB x reads)

        #pragma unroll
        for (int nt = 0; nt < 3; ++nt) {
            Frag bl0, bl1;                        // streamed from L2 (shared by both images)
            bl0.v = *(const bf16x8*)(ws + nt * 512 + lane * 8);
            bl1.v = *(const bf16x8*)(ws + (3 + nt) * 512 + lane * 8);
            f32x4 acc = {0.f, 0.f, 0.f, 0.f};
            acc = MFMA(a0.v, bl0.v, acc);
            acc = MFMA(a1.v, bl1.v, acc);
            const int j = 16 * nt + col16;                 // output k' index
            const int di = j / 12, dj = (j % 12) / 3, cch = j % 3;
            #pragma unroll
            for (int r = 0; r < 4; ++r) {
                const int blk = 16 * wv + 4 * grp + r;     // C row = block id
                const int row = (blk >> 3) * 4 + di, cp = (blk & 7) * 4 + dj;
                s_img[row * RS1 + cp * 4 + cch] = nbf(acc[r]);
            }
        }
    }
    // zero pad-channel 3, row pads (cols 128..159), LDS tails, h2b pads; fill addr tables
    for (int p = tid; p < 2048; p += 512) {                 // ch-3 of 1024 px per image
        unsigned short* si = s_pool + (p >> 10) * IMG_SZ;
        const int q = p & 1023;
        si[(q >> 5) * RS1 + (q & 31) * 4 + 3] = 0;
    }
    for (int p = tid; p < 2048; p += 512) {                 // 32 pad cols x 32 rows per image
        unsigned short* si = s_pool + (p >> 10) * IMG_SZ;
        const int q = p & 1023;
        si[(q >> 5) * RS1 + 128 + (q & 31)] = 0;
    }
    if (tid < 128) s_pool[(tid >> 6) * IMG_SZ + 32 * RS1 + (tid & 63)] = 0;
    if (tid < 128) s_h1[(tid >> 6) * H1_SZ + 14 * RS2 + (tid & 63)] = 0;
    if (tid < 24) s_h2b[(tid / 12) * 512 + 500 + (tid % 12)] = 0;
    if (tid < 196) {                                        // q -> (oi,oj) tables, once/block
        const int oi = tid / 14, oj = tid % 14;
        s_tA[tid] = (2 * oi) * RS1 + (2 * oj) * 4;
        s_tW[tid] = oi * RS2 + oj * 12;
    }
    __syncthreads();

    // ---------------- Phase 2: conv1+pool+relu via MFMA -> s_h1 (HWC12 bf16) ----------------
    // Two M-tiles/iter; bases from LDS tables (broadcast b32 reads, no divisions).
    {
        Frag bc1[5];
        #pragma unroll
        for (int f = 0; f < 5; ++f)
            bc1[f].v = *(const bf16x8*)(ws + (6 + f) * 512 + lane * 8);
        const float bias1 = b1[col16 < 10 ? col16 : 0];
        const int sub = col16 & 3, qc = col16 >> 2;
        const int laneA = (sub >> 1) * RS1 + (sub & 1) * 4 + 4 * grp;  // lane-const A offset
        const int qr = 4 * wv + qc;                 // read-table index base (+32u, +16 for pair)
        const int qw = 4 * wv + grp;                // write-table index base

        for (int u = 0; u < 6; ++u) {
            const int base0 = s_tA[qr + 32 * u]      + laneA;
            const int base1 = s_tA[qr + 32 * u + 16] + laneA;
            f32x4 acc0 = {0.f, 0.f, 0.f, 0.f}, acc1 = {0.f, 0.f, 0.f, 0.f};
            #pragma unroll
            for (int ky = 0; ky < 5; ++ky) {
                Frag a0, a1;
                a0.h[0] = *(const short4*)&s_img[base0 + ky * RS1];
                a0.h[1] = *(const short4*)&s_img[base0 + ky * RS1 + 16];
                a1.h[0] = *(const short4*)&s_img[base1 + ky * RS1];
                a1.h[1] = *(const short4*)&s_img[base1 + ky * RS1 + 16];
                acc0 = MFMA(a0.v, bc1[ky].v, acc0);
                acc1 = MFMA(a1.v, bc1[ky].v, acc1);
            }
            if (col16 < 12) {
                const float pm0 = fmaxf(fmaxf(acc0[0], acc0[1]), fmaxf(acc0[2], acc0[3]));
                const float pm1 = fmaxf(fmaxf(acc1[0], acc1[1]), fmaxf(acc1[2], acc1[3]));
                s_h1i[s_tW[qw + 32 * u]      + col16] =
                    (col16 < 10) ? nbf(fmaxf(pm0 + bias1, 0.f)) : (unsigned short)0;
                s_h1i[s_tW[qw + 32 * u + 16] + col16] =
                    (col16 < 10) ? nbf(fmaxf(pm1 + bias1, 0.f)) : (unsigned short)0;
            }
        }
        if (wv == 0) {                                     // tail tile t = 48 (quads 192..195)
            const int base = s_tA[192 + qc] + laneA;
            f32x4 acc = {0.f, 0.f, 0.f, 0.f};
            #pragma unroll
            for (int ky = 0; ky < 5; ++ky) {
                Frag a;
                a.h[0] = *(const short4*)&s_img[base + ky * RS1];
                a.h[1] = *(const short4*)&s_img[base + ky * RS1 + 16];
                acc = MFMA(a.v, bc1[ky].v, acc);
            }
            if (col16 < 12) {
                const float pm = fmaxf(fmaxf(acc[0], acc[1]), fmaxf(acc[2], acc[3]));
                s_h1i[s_tW[192 + grp] + col16] =
                    (col16 < 10) ? nbf(fmaxf(pm + bias1, 0.f)) : (unsigned short)0;
            }
        }
    }
    __syncthreads();

    // ---- re-stage conv2 B-frags (20KB) into s_pool (both s_img now dead) ----
    {
        const uint4* src = (const uint4*)(ws + 11 * 512);   // frags 11..30, 1280 uint4
        uint4* dst = (uint4*)s_pool;
        dst[tid]       = src[tid];
        dst[tid + 512] = src[tid + 512];
        if (tid < 256) dst[tid + 1024] = src[tid + 1024];
    }
    __syncthreads();

    // ---------------- Phase 3: conv2+pool+relu via MFMA -> s_h2b (bf16, flatten order) ----------------
    {
        const int oc1 = 16 + col16;
        const float bias20 = b2[col16];                    // col16 <= 15 < 20
        const float bias21 = b2[oc1 < 20 ? oc1 : 0];

        int baseA[2];
        #pragma unroll
        for (int tt = 0; tt < 2; ++tt) {
            const int t = wv + 4 * tt;                     // t in {wv, wv+4}
            int q = 4 * t + (col16 >> 2); if (q > 24) q = 24;   // clamp keeps reads in-bounds
            const int sub = col16 & 3;
            const int oi = q / 5, oj = q % 5;
            const int ci = 2 * oi + (sub >> 1), cj = 2 * oj + (sub & 1);
            baseA[tt] = ci * RS2 + cj * 12 + 4 * grp;
        }

        f32x4 accA0 = {0.f,0.f,0.f,0.f}, accA1 = {0.f,0.f,0.f,0.f};   // tile tt=0: N-tile 0/1
        f32x4 accB0 = {0.f,0.f,0.f,0.f}, accB1 = {0.f,0.f,0.f,0.f};   // tile tt=1
        #pragma unroll
        for (int ky = 0; ky < 5; ++ky) {
            #pragma unroll
            for (int s = 0; s < 2; ++s) {
                Frag bb0, bb1;
                bb0.v = *(const bf16x8*)(s_b2 + (ky * 2 + s) * 512 + lane * 8);
                bb1.v = *(const bf16x8*)(s_b2 + (10 + ky * 2 + s) * 512 + lane * 8);
                Frag a0, a1;
                a0.h[0] = *(const short4*)&s_h1i[baseA[0] + ky * RS2 + 32 * s];
                a0.h[1] = *(const short4*)&s_h1i[baseA[0] + ky * RS2 + 32 * s + 16];
                a1.h[0] = *(const short4*)&s_h1i[baseA[1] + ky * RS2 + 32 * s];
                a1.h[1] = *(const short4*)&s_h1i[baseA[1] + ky * RS2 + 32 * s + 16];
                accA0 = MFMA(a0.v, bb0.v, accA0);
                accA1 = MFMA(a0.v, bb1.v, accA1);
                accB0 = MFMA(a1.v, bb0.v, accB0);
                accB1 = MFMA(a1.v, bb1.v, accB1);
            }
        }
        unsigned short* h2 = s_h2b + img * 512;
        #pragma unroll
        for (int tt = 0; tt < 2; ++tt) {
            const int t = wv + 4 * tt;
            if (t < 7) {
                const f32x4 c0 = tt ? accB0 : accA0;
                const f32x4 c1 = tt ? accB1 : accA1;
                const int qo = 4 * t + grp;
                if (qo < 25) {
                    const float p0 = fmaxf(fmaxf(c0[0], c0[1]), fmaxf(c0[2], c0[3]));
                    h2[col16 * 25 + qo] = nbf(fmaxf(p0 + bias20, 0.f));
                    if (oc1 < 20) {
                        const float p1 = fmaxf(fmaxf(c1[0], c1[1]), fmaxf(c1[2], c1[3]));
                        h2[oc1 * 25 + qo] = nbf(fmaxf(p1 + bias21, 0.f));
                    }
                }
            }
        }
    }
    __syncthreads();

    // ---------------- Phase 4: fc1 via MFMA: C[out][img], wave = (khalf=img, mt=wv) ----------------
    {
        const int mt = wv, khalf = img;
        const int imc = col16 < 2 ? col16 : 0;     // B col = image; cols 2..15 unused
        f32x4 acc = {0.f, 0.f, 0.f, 0.f};
        #pragma unroll
        for (int j = 0; j < 8; ++j) {
            const int kstep = 8 * khalf + j;
            Frag af, bfv;
            af.v = *(const bf16x8*)(ws + 16384 + (kstep * 4 + mt) * 512 + lane * 8);
            bfv.h[0] = *(const short4*)&s_h2b[imc * 512 + 32 * kstep + 4 * grp];
            bfv.h[1] = *(const short4*)&s_h2b[imc * 512 + 32 * kstep + 16 + 4 * grp];
            acc = MFMA(af.v, bfv.v, acc);
        }
        if (col16 < 2) {
            #pragma unroll
            for (int r = 0; r < 4; ++r)
                s_part[(khalf * 2 + col16) * 64 + 16 * mt + 4 * grp + r] = acc[r];
        }
    }
    __syncthreads();
    if (tid < 128) {                                // combine k-halves, +bias, relu
        const int im = tid >> 6, o = tid & 63;
        const float a = s_part[im * 64 + o] + s_part[(2 + im) * 64 + o];
        if (o < 50) s_f1[im * 64 + o] = fmaxf(a + fb1[o], 0.f);
    }
    __syncthreads();

    // ---------------- Phase 5: fc2 (50->10), both images ----------------
    if (tid < 20) {
        const int im = (tid >= 10) ? 1 : 0;
        const int r = tid - 10 * im;
        const float* wr = fw2 + r * 50;
        const float* f1 = s_f1 + im * 64;
        float a = fb2[r];
        for (int k = 0; k < 50; ++k) a += f1[k] * wr[k];
        s_lg[im * 16 + r] = a;
    }
    __syncthreads();

    // ---------------- Phase 6: log_softmax, both images ----------------
    if (tid < 20) {
        const int im = (tid >= 10) ? 1 : 0;
        const int r = tid - 10 * im;
        const float* lg = s_lg + im * 16;
        float m = lg[0];
        for (int k = 1; k < 10; ++k) m = fmaxf(m, lg[k]);
        float s = 0.f;
        for (int k = 0; k < 10; ++k) s += expf(lg[k] - m);
        out[(2 * (size_t)blockIdx.x + im) * 10 + r] = lg[r] - m - logf(s);
    }
}

extern "C" void kernel_launch(void* const* d_in, const int* in_sizes, int n_in,
                              void* d_out, int out_size, void* d_ws, size_t ws_size,
                              hipStream_t stream) {
    const float* x   = (const float*)d_in[0];
    const float* W   = (const float*)d_in[1];
    const float* w1  = (const float*)d_in[2];
    const float* b1  = (const float*)d_in[3];
    const float* w2  = (const float*)d_in[4];
    const float* b2  = (const float*)d_in[5];
    const float* fw1 = (const float*)d_in[6];
    const float* fb1 = (const float*)d_in[7];
    const float* fw2 = (const float*)d_in[8];
    const float* fb2 = (const float*)d_in[9];
    float* o = (float*)d_out;
    unsigned short* wsp = (unsigned short*)d_ws;

    const int B = in_sizes[0] / 3072;
    prepack<<<dim3(31), dim3(64), 0, stream>>>(W, w1, w2, wsp);
    pack_fc1<<<dim3(64), dim3(64), 0, stream>>>(fw1, wsp);
    fused_net<<<dim3(B / 2), dim3(512), 0, stream>>>(x, wsp, b1, b2, fb1, fw2, fb2, o);
}